// Round 3
// baseline (207.412 us; speedup 1.0000x reference)
//
#include <hip/hip_runtime.h>
#include <cmath>

// Shapes fixed by reference: R=4096, F=256, K=8.
#define R 4096
#define F 256
#define NK 8

typedef _Float16 half8 __attribute__((ext_vector_type(8)));
typedef _Float16 half4v __attribute__((ext_vector_type(4)));
typedef float f32x4 __attribute__((ext_vector_type(4)));

#define LOG2E      1.4426950408889634f
#define LOG2LOG2E  0.5287663729448977f   // log2(log2(e))

// ---------------------------------------------------------------------------
// ws layout (bytes):
//   0          : x1h (4096*256 f16) 2 MB
//   2 MB       : x2h (4096*256 f16) 2 MB
//   4 MB +0    : r1   (4096 f32)
//       +16K   : sq1
//       +32K   : r2
//       +48K   : sq2
//       +64K   : S    (8*4096 f32, 128 KB)  phase0 denom -> finalize: w_k/S
//       +192K  : rA   (8*4096 f32, 128 KB)  c_k*(sq1-2m r1+Fm^2)+log2log2e
//       +320K  : cB   (8*4096 f32, 128 KB)  c_k*(sq2+2m r2)
//       +448K  : prm  (16 f32) [0..7]=w_k  [8..15]=g_k = 2*is2*log2e
// Math: t = c_k*dist + log2log2e, c_k = -is2*log2e, dist = row+col-2dot
//       => t = rA[k][i] + cB[k][j] + g_k*dot,  g_k = -2 c_k
//       kv*log2e = exp2(t);  exp(kv) = exp2(exp2(t)).
// ---------------------------------------------------------------------------

__global__ __launch_bounds__(256) void prep_kernel(
    const float* __restrict__ x1, const float* __restrict__ x2,
    const float* __restrict__ sigmas, const float* __restrict__ sigp,
    _Float16* __restrict__ x1h, _Float16* __restrict__ x2h,
    float* __restrict__ r1, float* __restrict__ sq1,
    float* __restrict__ r2, float* __restrict__ sq2,
    float* __restrict__ S, float* __restrict__ prm)
{
    const int tid  = threadIdx.x;
    const int wid  = tid >> 6;
    const int lane = tid & 63;
    const int row  = blockIdx.x * 4 + wid;   // 0..8191: x1 rows then x2 rows

    const float* src; _Float16* dsth; float* rs; float* rq; int r;
    if (row < R) { src = x1; dsth = x1h; rs = r1; rq = sq1; r = row; }
    else         { src = x2; dsth = x2h; rs = r2; rq = sq2; r = row - R; }

    float4 v = ((const float4*)(src + (size_t)r * F))[lane];
    half4v h = { (_Float16)v.x, (_Float16)v.y, (_Float16)v.z, (_Float16)v.w };
    *(half4v*)(dsth + (size_t)r * F + lane * 4) = h;

    float s = v.x + v.y + v.z + v.w;
    float q = v.x * v.x + v.y * v.y + v.z * v.z + v.w * v.w;
    for (int m = 1; m < 64; m <<= 1) {
        s += __shfl_xor(s, m);
        q += __shfl_xor(q, m);
    }
    if (lane == 0) { rs[r] = s; rq[r] = q; }

    // zero softmax-denominator accumulators (ws re-poisoned 0xAA each call)
    int g = blockIdx.x * 256 + tid;
    if (g < NK * R) S[g] = 0.f;

    if (blockIdx.x == 0 && tid == 0) {
        float w[NK], mx = -1e30f;
        for (int k = 0; k < NK; ++k) { float sp = sigp[k]; w[k] = 1.f / (sp * sp); mx = fmaxf(mx, w[k]); }
        float sum = 0.f;
        for (int k = 0; k < NK; ++k) { w[k] = expf(w[k] - mx); sum += w[k]; }
        for (int k = 0; k < NK; ++k) prm[k] = w[k] / sum;
        for (int k = 0; k < NK; ++k) {
            float sg = sigmas[k];
            float is2 = 1.f / (2.f * sg * sg);
            prm[8 + k] = 2.f * is2 * LOG2E;     // g_k
        }
    }
}

// rA[k][i], cB[k][j] from raw inputs (no prm dependency -> no race with prep)
__global__ __launch_bounds__(256) void prep2_kernel(
    const float* __restrict__ sigmas, const float* __restrict__ means,
    const float* __restrict__ r1, const float* __restrict__ sq1,
    const float* __restrict__ r2, const float* __restrict__ sq2,
    float* __restrict__ rA, float* __restrict__ cB)
{
    int idx  = blockIdx.x * 256 + threadIdx.x;   // 0..65535
    int half = idx >> 15;
    int k    = (idx >> 12) & 7;
    int i    = idx & 4095;
    float sg = sigmas[k], m = means[k];
    float c  = -LOG2E / (2.f * sg * sg);         // c_k
    if (half == 0)
        rA[k * R + i] = c * (sq1[i] - 2.f * m * r1[i] + (float)F * m * m) + LOG2LOG2E;
    else
        cB[k * R + i] = c * (sq2[i] + 2.f * m * r2[i]);
}

// S[k,i] <- w_k / S[k,i]
__global__ __launch_bounds__(256) void finalize_kernel(
    float* __restrict__ S, const float* __restrict__ prm)
{
    int g = blockIdx.x * 256 + threadIdx.x;   // 32768 total
    int k = g >> 12;
    S[g] = prm[k] / S[g];
}

// ---------------------------------------------------------------------------
// 64x128-tile fp16 MFMA GEMM (dot = x1 @ x2^T) + fused exp2 epilogue.
// 4 waves in 2x2 grid; wave = 32x64 quadrant -> acc[2][4] f32x4 (32 regs).
// After GEMM, rA/Sv (per-row) and cB (per-col) slices are cooperatively
// staged into the dead LDS buffers (strides 17/9 avoid bank conflicts), so
// the hot loop is pure VALU+trans: add, fma, 2x v_exp_f32, fma.
// ---------------------------------------------------------------------------
template <int PHASE>
__global__ __launch_bounds__(256, 4) void gemm_kernel(
    const _Float16* __restrict__ Ah, const _Float16* __restrict__ Bh,
    const float* __restrict__ rA, const float* __restrict__ cB,
    const float* __restrict__ prm, float* __restrict__ S, float* __restrict__ out)
{
    constexpr int SK = 72;  // 64 + 8-half pad
    __shared__ _Float16 As[64 * SK];    //  9.2 KB
    __shared__ _Float16 Bs[128 * SK];   // 18.4 KB
    float* rowSt = (float*)As;          // [64][17]: 0..7 rA_k, 8..15 Sv_k
    float* colSt = (float*)Bs;          // [128][9]: 0..7 cB_k

    const int tid  = threadIdx.x;
    const int lane = tid & 63;
    const int wid  = tid >> 6;
    const int wm   = wid >> 1, wn = wid & 1;
    const int q    = lane >> 4, m16 = lane & 15;
    const int tm   = blockIdx.y, tn = blockIdx.x;

    f32x4 acc[2][4];
#pragma unroll
    for (int a = 0; a < 2; ++a)
#pragma unroll
        for (int b = 0; b < 4; ++b)
            acc[a][b] = (f32x4){0.f, 0.f, 0.f, 0.f};

    const size_t abase = (size_t)(tm * 64) * F;
    const size_t bbase = (size_t)(tn * 128) * F;

    for (int k0 = 0; k0 < F; k0 += 64) {
#pragma unroll
        for (int c = 0; c < 2; ++c) {          // A: 64x64 halves, 2 chunks/thr
            int idx = c * 256 + tid;
            int row = idx >> 3, c8 = (idx & 7) * 8;
            *(uint4*)&As[row * SK + c8] =
                *(const uint4*)&Ah[abase + (size_t)row * F + k0 + c8];
        }
#pragma unroll
        for (int c = 0; c < 4; ++c) {          // B: 128x64 halves, 4 chunks/thr
            int idx = c * 256 + tid;
            int row = idx >> 3, c8 = (idx & 7) * 8;
            *(uint4*)&Bs[row * SK + c8] =
                *(const uint4*)&Bh[bbase + (size_t)row * F + k0 + c8];
        }
        __syncthreads();
#pragma unroll
        for (int s = 0; s < 2; ++s) {
            half8 a[2], b[4];
#pragma unroll
            for (int mt = 0; mt < 2; ++mt)
                a[mt] = *(const half8*)&As[(wm * 32 + mt * 16 + m16) * SK + s * 32 + q * 8];
#pragma unroll
            for (int nt = 0; nt < 4; ++nt)
                b[nt] = *(const half8*)&Bs[(wn * 64 + nt * 16 + m16) * SK + s * 32 + q * 8];
#pragma unroll
            for (int mt = 0; mt < 2; ++mt)
#pragma unroll
                for (int nt = 0; nt < 4; ++nt)
                    acc[mt][nt] = __builtin_amdgcn_mfma_f32_16x16x32_f16(
                        a[mt], b[nt], acc[mt][nt], 0, 0, 0);
        }
        __syncthreads();
    }

    // ---- stage epilogue operands into (now dead) LDS ----
#pragma unroll
    for (int c = 0; c < 4; ++c) {               // rowSt: 64 x 16 = 1024 vals
        int id2 = c * 256 + tid;
        int row = id2 >> 4, slot = id2 & 15;
        float v;
        if (slot < 8) v = rA[slot * R + tm * 64 + row];
        else          v = (PHASE == 1) ? S[(slot - 8) * R + tm * 64 + row] : 0.f;
        rowSt[row * 17 + slot] = v;
    }
#pragma unroll
    for (int c = 0; c < 4; ++c) {               // colSt: 128 x 8 = 1024 vals
        int id2 = c * 256 + tid;
        int col = id2 >> 3, k = id2 & 7;
        colSt[col * 9 + k] = cB[k * R + tn * 128 + col];
    }
    __syncthreads();

    float g[8];
#pragma unroll
    for (int k = 0; k < 8; ++k) g[k] = prm[8 + k];   // uniform -> SGPR

    float colQ[4][8];
#pragma unroll
    for (int nt = 0; nt < 4; ++nt) {
        int col = wn * 64 + nt * 16 + m16;
#pragma unroll
        for (int k = 0; k < 8; ++k) colQ[nt][k] = colSt[col * 9 + k];
    }

#pragma unroll
    for (int mt = 0; mt < 2; ++mt) {
#pragma unroll
        for (int r = 0; r < 4; ++r) {
            int rowl = wm * 32 + mt * 16 + q * 4 + r;     // local row 0..63
            float rAv[8];
#pragma unroll
            for (int k = 0; k < 8; ++k) rAv[k] = rowSt[rowl * 17 + k];

            if (PHASE == 0) {
                float tk[8];
#pragma unroll
                for (int k = 0; k < 8; ++k) tk[k] = 0.f;
#pragma unroll
                for (int nt = 0; nt < 4; ++nt) {
                    float d = acc[mt][nt][r];
#pragma unroll
                    for (int k = 0; k < 8; ++k) {
                        float t = fmaf(g[k], d, rAv[k] + colQ[nt][k]);
                        tk[k] += __builtin_amdgcn_exp2f(__builtin_amdgcn_exp2f(t));
                    }
                }
#pragma unroll
                for (int k = 0; k < 8; ++k) {
                    float t = tk[k];
                    t += __shfl_xor(t, 1); t += __shfl_xor(t, 2);
                    t += __shfl_xor(t, 4); t += __shfl_xor(t, 8);
                    if (m16 == 0) atomicAdd(&S[k * R + tm * 64 + rowl], t);
                }
            } else {
                float sv[8];
#pragma unroll
                for (int k = 0; k < 8; ++k) sv[k] = rowSt[rowl * 17 + 8 + k];
                int rowg = tm * 64 + rowl;
#pragma unroll
                for (int nt = 0; nt < 4; ++nt) {
                    float d = acc[mt][nt][r];
                    float o = 0.f;
#pragma unroll
                    for (int k = 0; k < 8; ++k) {
                        float t = fmaf(g[k], d, rAv[k] + colQ[nt][k]);
                        o = fmaf(sv[k], __builtin_amdgcn_exp2f(__builtin_amdgcn_exp2f(t)), o);
                    }
                    int colg = tn * 128 + wn * 64 + nt * 16 + m16;
                    __builtin_nontemporal_store(o, &out[(size_t)rowg * R + colg]);
                }
            }
        }
    }
}

extern "C" void kernel_launch(void* const* d_in, const int* in_sizes, int n_in,
                              void* d_out, int out_size, void* d_ws, size_t ws_size,
                              hipStream_t stream) {
    (void)in_sizes; (void)n_in; (void)out_size; (void)ws_size;
    const float* x1     = (const float*)d_in[0];
    const float* x2     = (const float*)d_in[1];
    const float* sigmas = (const float*)d_in[2];
    const float* means  = (const float*)d_in[3];
    const float* sigp   = (const float*)d_in[4];
    float* out = (float*)d_out;

    char* ws = (char*)d_ws;
    _Float16* x1h = (_Float16*)ws;
    _Float16* x2h = (_Float16*)(ws + 2097152);
    float* r1  = (float*)(ws + 4194304);
    float* sq1 = (float*)(ws + 4194304 + 16384);
    float* r2  = (float*)(ws + 4194304 + 32768);
    float* sq2 = (float*)(ws + 4194304 + 49152);
    float* S   = (float*)(ws + 4194304 + 65536);
    float* rA  = (float*)(ws + 4194304 + 196608);
    float* cB  = (float*)(ws + 4194304 + 327680);
    float* prm = (float*)(ws + 4194304 + 458752);

    prep_kernel<<<2048, 256, 0, stream>>>(x1, x2, sigmas, sigp,
                                          x1h, x2h, r1, sq1, r2, sq2, S, prm);
    prep2_kernel<<<256, 256, 0, stream>>>(sigmas, means, r1, sq1, r2, sq2, rA, cB);
    gemm_kernel<0><<<dim3(32, 64), 256, 0, stream>>>(x1h, x2h, rA, cB, prm, S, out);
    finalize_kernel<<<128, 256, 0, stream>>>(S, prm);
    gemm_kernel<1><<<dim3(32, 64), 256, 0, stream>>>(x1h, x2h, rA, cB, prm, S, out);
}

// Round 4
// 181.861 us; speedup vs baseline: 1.1405x; 1.1405x over previous
//
#include <hip/hip_runtime.h>
#include <cmath>

// Shapes fixed by reference: R=4096, F=256, K=8.
#define R 4096
#define F 256
#define NK 8

typedef _Float16 half8 __attribute__((ext_vector_type(8)));
typedef _Float16 half4v __attribute__((ext_vector_type(4)));
typedef float f32x4 __attribute__((ext_vector_type(4)));

#define LOG2E      1.4426950408889634f
#define LOG2LOG2E  0.5287663729448977f   // log2(log2(e))

// ---------------------------------------------------------------------------
// ws layout (bytes):
//   0          : x1h (4096*256 f16) 2 MB
//   2 MB       : x2h (4096*256 f16) 2 MB
//   4 MB +0    : r1 / +16K sq1 / +32K r2 / +48K sq2   (4096 f32 each)
//       +64K   : S   (8*4096 f32)  phase0 denom -> finalize: w_k/S
//       +192K  : rA  (8*4096 f32)  c_k*(sq1-2m r1+Fm^2)+log2log2e
//       +320K  : cB  (8*4096 f32)  c_k*(sq2+2m r2)
//       +448K  : prm (16 f32) [0..7]=w_k  [8..15]=g_k = 2*is2*log2e
// Math: c_k = -log2e/(2 s_k^2); t = rA[k][i]+cB[k][j]+g_k*dot,  g_k = -2 c_k
//       exp(kv) = exp2(exp2(t)).  dist in [~150,~6600] so clamps never bind.
// ---------------------------------------------------------------------------

__global__ __launch_bounds__(256) void prep_kernel(
    const float* __restrict__ x1, const float* __restrict__ x2,
    const float* __restrict__ sigmas, const float* __restrict__ sigp,
    _Float16* __restrict__ x1h, _Float16* __restrict__ x2h,
    float* __restrict__ r1, float* __restrict__ sq1,
    float* __restrict__ r2, float* __restrict__ sq2,
    float* __restrict__ S, float* __restrict__ prm)
{
    const int tid  = threadIdx.x;
    const int wid  = tid >> 6;
    const int lane = tid & 63;
    const int row  = blockIdx.x * 4 + wid;   // 0..8191: x1 rows then x2 rows

    const float* src; _Float16* dsth; float* rs; float* rq; int r;
    if (row < R) { src = x1; dsth = x1h; rs = r1; rq = sq1; r = row; }
    else         { src = x2; dsth = x2h; rs = r2; rq = sq2; r = row - R; }

    float4 v = ((const float4*)(src + (size_t)r * F))[lane];
    half4v h = { (_Float16)v.x, (_Float16)v.y, (_Float16)v.z, (_Float16)v.w };
    *(half4v*)(dsth + (size_t)r * F + lane * 4) = h;

    float s = v.x + v.y + v.z + v.w;
    float q = v.x * v.x + v.y * v.y + v.z * v.z + v.w * v.w;
    for (int m = 1; m < 64; m <<= 1) {
        s += __shfl_xor(s, m);
        q += __shfl_xor(q, m);
    }
    if (lane == 0) { rs[r] = s; rq[r] = q; }

    int g = blockIdx.x * 256 + tid;
    if (g < NK * R) S[g] = 0.f;

    if (blockIdx.x == 0 && tid == 0) {
        float w[NK], mx = -1e30f;
        for (int k = 0; k < NK; ++k) { float sp = sigp[k]; w[k] = 1.f / (sp * sp); mx = fmaxf(mx, w[k]); }
        float sum = 0.f;
        for (int k = 0; k < NK; ++k) { w[k] = expf(w[k] - mx); sum += w[k]; }
        for (int k = 0; k < NK; ++k) prm[k] = w[k] / sum;
        for (int k = 0; k < NK; ++k) {
            float sg = sigmas[k];
            prm[8 + k] = LOG2E / (sg * sg);     // g_k = 2*is2*log2e
        }
    }
}

// rA[k][i], cB[k][j] from raw inputs
__global__ __launch_bounds__(256) void prep2_kernel(
    const float* __restrict__ sigmas, const float* __restrict__ means,
    const float* __restrict__ r1, const float* __restrict__ sq1,
    const float* __restrict__ r2, const float* __restrict__ sq2,
    float* __restrict__ rA, float* __restrict__ cB)
{
    int idx  = blockIdx.x * 256 + threadIdx.x;   // 0..65535
    int half = idx >> 15;
    int k    = (idx >> 12) & 7;
    int i    = idx & 4095;
    float sg = sigmas[k], m = means[k];
    float c  = -LOG2E / (2.f * sg * sg);         // c_k
    if (half == 0)
        rA[k * R + i] = c * (sq1[i] - 2.f * m * r1[i] + (float)F * m * m) + LOG2LOG2E;
    else
        cB[k * R + i] = c * (sq2[i] + 2.f * m * r2[i]);
}

// S[k,i] <- w_k / S[k,i]
__global__ __launch_bounds__(256) void finalize_kernel(
    float* __restrict__ S, const float* __restrict__ prm)
{
    int g = blockIdx.x * 256 + threadIdx.x;   // 32768 total
    int k = g >> 12;
    S[g] = prm[k] / S[g];
}

// ---------------------------------------------------------------------------
// 128x128-tile fp16 MFMA GEMM (dot = x1 @ x2^T) + fused exp2 epilogue.
// R2 geometry restored: (256,2) so the compiler has register room to batch
// memory ops (R3's (256,4) gave VGPR=48 and serialized loads -> 97 us/pass).
// PHASE 0: S[k,i] += sum_j exp2(exp2(t))   (quad-shuffle + atomicAdd)
// PHASE 1: out[i,j] = sum_k (w_k/S[k,i]) * exp2(exp2(t))   (S pre-inverted)
// ---------------------------------------------------------------------------
template <int PHASE>
__global__ __launch_bounds__(256, 2) void gemm_kernel(
    const _Float16* __restrict__ Ah, const _Float16* __restrict__ Bh,
    const float* __restrict__ rA, const float* __restrict__ cB,
    const float* __restrict__ prm, float* __restrict__ S, float* __restrict__ out)
{
    constexpr int SK = 72;  // 64 + 8-half pad: 2-way bank alias (free)
    __shared__ _Float16 As[128 * SK];
    __shared__ _Float16 Bs[128 * SK];

    const int tid  = threadIdx.x;
    const int lane = tid & 63;
    const int wid  = tid >> 6;
    const int wm   = wid >> 1, wn = wid & 1;   // 2x2 waves of 64x64
    const int q    = lane >> 4, m16 = lane & 15;
    const int tm   = blockIdx.y, tn = blockIdx.x;

    f32x4 acc[4][4];
#pragma unroll
    for (int a = 0; a < 4; ++a)
#pragma unroll
        for (int b = 0; b < 4; ++b)
            acc[a][b] = (f32x4){0.f, 0.f, 0.f, 0.f};

    for (int k0 = 0; k0 < F; k0 += 64) {
#pragma unroll
        for (int c = 0; c < 4; ++c) {
            int idx = c * 256 + tid;         // 0..1023 chunks of 8 halves
            int row = idx >> 3, c8 = (idx & 7) * 8;
            *(uint4*)&As[row * SK + c8] =
                *(const uint4*)&Ah[(size_t)(tm * 128 + row) * F + k0 + c8];
            *(uint4*)&Bs[row * SK + c8] =
                *(const uint4*)&Bh[(size_t)(tn * 128 + row) * F + k0 + c8];
        }
        __syncthreads();
#pragma unroll
        for (int s = 0; s < 2; ++s) {
            half8 a[4], b[4];
#pragma unroll
            for (int mt = 0; mt < 4; ++mt)
                a[mt] = *(const half8*)&As[(wm * 64 + mt * 16 + m16) * SK + s * 32 + q * 8];
#pragma unroll
            for (int nt = 0; nt < 4; ++nt)
                b[nt] = *(const half8*)&Bs[(wn * 64 + nt * 16 + m16) * SK + s * 32 + q * 8];
#pragma unroll
            for (int mt = 0; mt < 4; ++mt)
#pragma unroll
                for (int nt = 0; nt < 4; ++nt)
                    acc[mt][nt] = __builtin_amdgcn_mfma_f32_16x16x32_f16(
                        a[mt], b[nt], acc[mt][nt], 0, 0, 0);
        }
        __syncthreads();
    }

    // ---- epilogue ----
    float g[8];
#pragma unroll
    for (int k = 0; k < 8; ++k) g[k] = prm[8 + k];   // uniform -> SGPR

    int colg[4];
    float colQ[8][4];
#pragma unroll
    for (int nt = 0; nt < 4; ++nt) {
        colg[nt] = tn * 128 + wn * 64 + nt * 16 + m16;
#pragma unroll
        for (int k = 0; k < 8; ++k) colQ[k][nt] = cB[k * R + colg[nt]];
    }

#pragma unroll
    for (int mt = 0; mt < 4; ++mt) {
#pragma unroll
        for (int r = 0; r < 4; ++r) {
            int rowg = tm * 128 + wm * 64 + mt * 16 + q * 4 + r;
            float rAv[8];
#pragma unroll
            for (int k = 0; k < 8; ++k) rAv[k] = rA[k * R + rowg];

            if (PHASE == 0) {
#pragma unroll
                for (int k = 0; k < 8; ++k) {
                    float t = 0.f;
#pragma unroll
                    for (int nt = 0; nt < 4; ++nt) {
                        float tt = fmaf(g[k], acc[mt][nt][r], rAv[k] + colQ[k][nt]);
                        t += __builtin_amdgcn_exp2f(__builtin_amdgcn_exp2f(tt));
                    }
                    t += __shfl_xor(t, 1); t += __shfl_xor(t, 2);
                    t += __shfl_xor(t, 4); t += __shfl_xor(t, 8);
                    if (m16 == 0) atomicAdd(&S[k * R + rowg], t);
                }
            } else {
                float sv[8];
#pragma unroll
                for (int k = 0; k < 8; ++k) sv[k] = S[k * R + rowg];  // = w_k/denom
#pragma unroll
                for (int nt = 0; nt < 4; ++nt) {
                    float d = acc[mt][nt][r];
                    float o = 0.f;
#pragma unroll
                    for (int k = 0; k < 8; ++k) {
                        float tt = fmaf(g[k], d, rAv[k] + colQ[k][nt]);
                        o = fmaf(sv[k], __builtin_amdgcn_exp2f(__builtin_amdgcn_exp2f(tt)), o);
                    }
                    __builtin_nontemporal_store(o, &out[(size_t)rowg * R + colg[nt]]);
                }
            }
        }
    }
}

extern "C" void kernel_launch(void* const* d_in, const int* in_sizes, int n_in,
                              void* d_out, int out_size, void* d_ws, size_t ws_size,
                              hipStream_t stream) {
    (void)in_sizes; (void)n_in; (void)out_size; (void)ws_size;
    const float* x1     = (const float*)d_in[0];
    const float* x2     = (const float*)d_in[1];
    const float* sigmas = (const float*)d_in[2];
    const float* means  = (const float*)d_in[3];
    const float* sigp   = (const float*)d_in[4];
    float* out = (float*)d_out;

    char* ws = (char*)d_ws;
    _Float16* x1h = (_Float16*)ws;
    _Float16* x2h = (_Float16*)(ws + 2097152);
    float* r1  = (float*)(ws + 4194304);
    float* sq1 = (float*)(ws + 4194304 + 16384);
    float* r2  = (float*)(ws + 4194304 + 32768);
    float* sq2 = (float*)(ws + 4194304 + 49152);
    float* S   = (float*)(ws + 4194304 + 65536);
    float* rA  = (float*)(ws + 4194304 + 196608);
    float* cB  = (float*)(ws + 4194304 + 327680);
    float* prm = (float*)(ws + 4194304 + 458752);

    prep_kernel<<<2048, 256, 0, stream>>>(x1, x2, sigmas, sigp,
                                          x1h, x2h, r1, sq1, r2, sq2, S, prm);
    prep2_kernel<<<256, 256, 0, stream>>>(sigmas, means, r1, sq1, r2, sq2, rA, cB);
    gemm_kernel<0><<<dim3(32, 32), 256, 0, stream>>>(x1h, x2h, rA, cB, prm, S, out);
    finalize_kernel<<<128, 256, 0, stream>>>(S, prm);
    gemm_kernel<1><<<dim3(32, 32), 256, 0, stream>>>(x1h, x2h, rA, cB, prm, S, out);
}